// Round 7
// baseline (161.333 us; speedup 1.0000x reference)
//
#include <hip/hip_runtime.h>
#include <stdint.h>

#define N_ANCH 25200
#define NCLS   80
#define KSEL   2048
#define MAXDET 1000
#define CONF_T 0.4f
#define IOU_T  0.45f
#define MAX_WH 7680.0f
#define HBINS  512
#define HBASE  0xBE00u
#define NCAND_MAX 4096
#define NSB    788                  // prep blocks (32 anchors each)
#define NIB    400                  // img blocks (4 full px/thread)
#define SUPCAP 224                  // max flagged rows held in LDS
#define RKB    512                  // rank blocks (8 items each, 32 lanes/item)
#define ROUGH_MAX 25216             // >= N_ANCH -> append can never overflow

// workspace layout (ws is ~267 MB per harness fill; we use < 1.5 MB)
#define WS_SELSCORE  0              // float  [2048]
#define WS_SELBOX    8192           // float4 [2048]
#define WS_DETCAND   40960          // float  [2048*6]     ends 90112
#define WS_ROUGH     98304          // u64    [25216]      ends 300032
#define WS_MASK      327680         // uint32 MT[64][2048]  ends 851968
#define WS_MTT       851968         // uint32 MTT[2048][64] ends 1376256
#define WS_F         1376256        // uint32 f[64] row-has-suppression bitmap

// Self-restoring cross-dispatch state: zeroed at module load (.bss), reset by
// nms (last kernel of every run) for the NEXT graph replay. No memset
// dispatch, no intra-dispatch zero race, no spin (R3 lesson).
__device__ uint32_t g_cnt;          // rough-candidate count
__device__ uint32_t g_hist[HBINS];  // 512-bin key histogram

// ------------------------------------------------------------ prep+img kernel
// blocks [0,NSB): score/key per anchor (8 lanes/anchor, strided class loads,
//   shuffle argmax: exact product compare, first-occurrence ties). Candidates
//   (v > CONF_T, ~15K expected) appended to rough[] via ONE block-level
//   atomicAdd (ballot aggregation) + per-candidate hist atomicAdd (512 bins,
//   negligible contention). Pack = key<<32 | ~(idx<<7|cls): idx-major tie
//   order == ref top_k stability; cls rides along (no cls array).
// blocks [NSB,NSB+NIB): img transform. 4 full px/thread (3x int4 = 12 ints),
//   one coalesced float4 per channel plane. x[c][p] = img[p][2-c]/255.
// Block 0 zeroes fglob (consumed 2 boundaries later; boundaries flush).
__global__ void __launch_bounds__(256)
prep_img_kernel(const float* __restrict__ pred0, const int* __restrict__ img,
                float* __restrict__ xout, unsigned long long* __restrict__ rough,
                uint32_t* __restrict__ fglob) {
    int tid = threadIdx.x;
    int bid = blockIdx.x;
    if (bid == 0 && tid < 64) fglob[tid] = 0u;

    if (bid >= NSB) {                          // ---- img role
        int i = (bid - NSB) * 256 + tid;       // < 102400 exactly (NIB*256)
        const int4* im4 = (const int4*)(img + (size_t)i * 12);  // 48B-aligned
        int4 va = im4[0], vb4 = im4[1], vc = im4[2];
        int p0 = i * 4;
        // ints: [0]p0r [1]p0g [2]p0b [3]p1r [4]p1g [5]p1b ... [11]p3b
        float4 o0 = make_float4((float)va.z / 255.0f, (float)vb4.y / 255.0f,
                                (float)vc.x / 255.0f, (float)vc.w / 255.0f);
        float4 o1 = make_float4((float)va.y / 255.0f, (float)vb4.x / 255.0f,
                                (float)vb4.w / 255.0f, (float)vc.z / 255.0f);
        float4 o2 = make_float4((float)va.x / 255.0f, (float)va.w / 255.0f,
                                (float)vb4.z / 255.0f, (float)vc.y / 255.0f);
        *(float4*)(xout + p0)          = o0;   // plane 0 = img ch 2 (b)
        *(float4*)(xout + 409600 + p0) = o1;   // plane 1 = img ch 1 (g)
        *(float4*)(xout + 819200 + p0) = o2;   // plane 2 = img ch 0 (r)
        return;
    }

    // ---- prep role
    __shared__ int wtot[4];
    __shared__ int s_base;
    int lane = tid & 63, wave = tid >> 6;
    int g = lane >> 3, l = lane & 7;
    int a = bid * 32 + wave * 8 + g;
    bool valid = (a < N_ANCH);
    float v = -1e30f; int ci = 0;
    if (valid) {
        const float* p = pred0 + (size_t)a * 85;
        float obj = p[4];
        #pragma unroll
        for (int k = 0; k < 10; ++k) {
            int c = l + 8 * k;                 // classes 0..79 exactly
            float x = p[5 + c] * obj;          // exact product compare (ref)
            if (x > v) { v = x; ci = c; }      // increasing c: > = first occurrence
        }
        #pragma unroll
        for (int m = 1; m < 8; m <<= 1) {
            float ov = __shfl_xor(v, m, 64);
            int   oc = __shfl_xor(ci, m, 64);
            if (ov > v || (ov == v && oc < ci)) { v = ov; ci = oc; }
        }
    }
    bool cand = valid && (l == 0) && (v > CONF_T);
    unsigned long long bm = __ballot(cand);    // bits only at lanes 0,8,..,56
    if (lane == 0) wtot[wave] = __popcll(bm);
    __syncthreads();
    if (tid == 0) {
        int t = 0;
        #pragma unroll
        for (int w = 0; w < 4; ++w) { int x = wtot[w]; wtot[w] = t; t += x; }
        s_base = (t > 0) ? (int)atomicAdd(&g_cnt, (uint32_t)t) : 0;
    }
    __syncthreads();
    if (cand) {
        uint32_t key = __float_as_uint(v) | 0x80000000u;   // v > 0.4 > 0
        int pos = s_base + wtot[wave]
                + (int)__popcll(bm & ((1ull << (g * 8)) - 1ull));
        rough[pos] = ((unsigned long long)key << 32)
                   | (uint32_t)~(((uint32_t)a << 7) | (uint32_t)ci);
        atomicAdd(&g_hist[(key >> 16) - HBASE], 1u);  // key(0.4)=0xBECC.. >= HBASE
    }
}

// ---------------------------------------------------------------- rank kernel
// Replaces compact+rank (R5 retry, fixed: no hist rebuild, 512 full-occupancy
// blocks, no per-iter barriers, unrolled streams). Per block:
//  1) load prepared g_hist -> LDS, suffix-scan -> lim (r10 lesson: ~15K
//     candidates exceed CONF_T, the hist-derived lim is ESSENTIAL).
//  2) stream rough[0..g_cnt) twice (L2-broadcast, ~120KB): pass A per-thread
//     count of items >= lim; ONE block scan; pass B scatter into LDS bag.
//     Bag order = (tid-strided, per-thread-contiguous) — NOT rough order, but
//     IDENTICAL across blocks (same array + same mapping) and rank-by-count
//     is order-independent -> slots 0..2047 still written exactly once.
//  3) rank 8 items, 32 lanes/item, 8-deep unrolled LDS reads (R6 lesson:
//     rank is latency-bound); emit at slot = rank.
__global__ void __launch_bounds__(256)
rank_kernel(const unsigned long long* __restrict__ rough,
            const float* __restrict__ pred0, float* __restrict__ sel_score,
            float4* __restrict__ selbox, float* __restrict__ det_cand) {
    __shared__ uint32_t h[HBINS];
    __shared__ unsigned long long s_it[NCAND_MAX];   // 32 KB
    __shared__ uint32_t s_lim;
    __shared__ int wt4[4];
    __shared__ int s_n;
    int tid = threadIdx.x, lane = tid & 63, wv = tid >> 6;
    int cnt = (int)g_cnt;

    // ---- 1) hist -> lim
    h[tid] = g_hist[tid]; h[tid + 256] = g_hist[tid + 256];
    if (tid == 0) s_lim = (HBASE << 16);
    __syncthreads();
    for (int off = 1; off < HBINS; off <<= 1) {      // suffix scan
        uint32_t a0 = h[tid] + ((tid + off < HBINS) ? h[tid + off] : 0u);
        uint32_t a1 = h[tid + 256] + ((tid + 256 + off < HBINS) ? h[tid + 256 + off] : 0u);
        __syncthreads();
        h[tid] = a0; h[tid + 256] = a1;
        __syncthreads();
    }
    for (int b = tid; b < HBINS; b += 256) {
        uint32_t sb  = h[b];
        uint32_t sb1 = (b < HBINS - 1) ? h[b + 1] : 0u;
        if (sb >= KSEL && sb1 < KSEL) s_lim = (uint32_t)(HBASE + b) << 16;
    }
    __syncthreads();
    uint32_t lim = s_lim;

    // ---- 2a) pass A: per-thread count (no barriers in the stream)
    int my = 0;
    #pragma unroll 4
    for (int i = tid; i < cnt; i += 256)
        my += ((uint32_t)(rough[i] >> 32) >= lim) ? 1 : 0;
    int pre = my;                                    // block scan
    #pragma unroll
    for (int o = 1; o < 64; o <<= 1) {
        int v = __shfl_up(pre, o, 64);
        if (lane >= o) pre += v;
    }
    if (lane == 63) wt4[wv] = pre;
    __syncthreads();
    if (tid == 0) {
        int t = 0;
        #pragma unroll
        for (int w = 0; w < 4; ++w) { int x = wt4[w]; wt4[w] = t; t += x; }
        s_n = t;
    }
    __syncthreads();
    int n = min(s_n, NCAND_MAX);
    int base = blockIdx.x * 8;
    if (base >= n) return;                           // block-uniform early exit

    // ---- 2b) pass B: deterministic scatter (L2-hot reload)
    int pos = wt4[wv] + (pre - my);                  // exclusive per-thread base
    #pragma unroll 4
    for (int i = tid; i < cnt; i += 256) {
        unsigned long long it = rough[i];
        if ((uint32_t)(it >> 32) >= lim) {
            if (pos < NCAND_MAX) s_it[pos] = it;
            ++pos;
        }
    }
    __syncthreads();

    // ---- 3) rank
    int grp = tid >> 5, s32 = tid & 31;
    int it_i = base + grp;
    if (it_i < n) {                                  // uniform within 32-lane group
        unsigned long long mine = s_it[it_i];
        int c = 0;
        #pragma unroll 8
        for (int t = s32; t < n; t += 32)            // independent LDS reads
            c += (s_it[t] > mine) ? 1 : 0;
        #pragma unroll
        for (int m = 1; m < 32; m <<= 1) c += __shfl_xor(c, m, 64);  // 32-half
        if (s32 == 0 && c < KSEL) {
            uint32_t key = (uint32_t)(mine >> 32);
            uint32_t u = ~(uint32_t)mine;
            int ai = (int)(u >> 7);
            int ci = (int)(u & 127u);
            float score = __uint_as_float(key & 0x7FFFFFFFu);
            const float* p = pred0 + (size_t)ai * 85;
            float x = p[0], y = p[1], w = p[2], hh = p[3];
            float x1 = x - w * 0.5f, y1 = y - hh * 0.5f;
            float x2 = x + w * 0.5f, y2 = y + hh * 0.5f;
            float cf = (float)ci;
            float off = cf * MAX_WH;
            selbox[c] = make_float4(x1 + off, y1 + off, x2 + off, y2 + off);
            float* dc = det_cand + (size_t)c * 6;
            dc[0] = x1; dc[1] = y1; dc[2] = x2; dc[3] = y2; dc[4] = score; dc[5] = cf;
            sel_score[c] = score;
        }
    }
}

// ----------------------------------------------------------------- mask kernel
// 512 blocks: block (wi = blk>>3, rg = blk&7) computes MT[wi][rg*256+tid]
// (coalesced) + transposed MTT[row][wi] (makes nms gather coalesced) + f
// bitmap via one ballot per wave -> atomicOr. Plain stores: the dispatch
// boundary to nms provides cross-XCD coherence (R4 lesson: sc1 costs more).
__global__ void __launch_bounds__(256)
mask_kernel(const float4* __restrict__ selbox, uint32_t* __restrict__ MT,
            uint32_t* __restrict__ MTT, uint32_t* __restrict__ fglob) {
    __shared__ float4 jb[32];
    int tid = threadIdx.x;
    int lane = tid & 63, wv = tid >> 6;
    int wi = blockIdx.x >> 3, rg = blockIdx.x & 7;

    if (tid < 32) jb[tid] = selbox[wi * 32 + tid];
    __syncthreads();
    int row = rg * 256 + tid;
    float4 a = selbox[row];
    float areaA = (a.z - a.x) * (a.w - a.y);
    uint32_t bits = 0;
    #pragma unroll 4
    for (int b = 0; b < 32; ++b) {
        int j = wi * 32 + b;
        if (j > row) {
            float4 q = jb[b];
            float lx = fmaxf(a.x, q.x), ly = fmaxf(a.y, q.y);
            float rx = fminf(a.z, q.z), ry = fminf(a.w, q.w);
            float ww = fmaxf(rx - lx, 0.0f), hh = fmaxf(ry - ly, 0.0f);
            float inter = ww * hh;
            float areaB = (q.z - q.x) * (q.w - q.y);
            float iou = inter / (areaA + areaB - inter + 1e-7f);
            if (iou > IOU_T) bits |= (1u << b);
        }
    }
    MT[(size_t)wi * 2048 + row] = bits;
    MTT[(size_t)row * 64 + wi] = bits;
    unsigned long long bm = __ballot(bits != 0u);   // wave = 64 rows = 2 words
    if (lane == 0) {
        int wbase = rg * 8 + wv * 2;
        uint32_t lo = (uint32_t)bm, hi = (uint32_t)(bm >> 32);
        if (lo) atomicOr(&fglob[wbase], lo);
        if (hi) atomicOr(&fglob[wbase + 1], hi);
    }
}

// ------------------------------------------------------------------ nms kernel
// One block. FIRST: reset g_cnt/g_hist for the next graph replay (consumed
// across the replay boundary -> coherent). Then: read f[64]; rowlist build;
// gather flagged rows from MTT (coalesced 256B/row, 16 in flight); one-wave
// sparse walk; emit + zero-fill.
__global__ void __launch_bounds__(256)
nms_kernel(const uint32_t* __restrict__ MT, const uint32_t* __restrict__ MTT,
           const uint32_t* __restrict__ fglob, const float* __restrict__ sel_score,
           const float* __restrict__ det_cand, float* __restrict__ det) {
    __shared__ __align__(16) uint32_t sup[SUPCAP * 64];  // 56 KB
    __shared__ uint32_t f_s[64];
    __shared__ int rowlist[SUPCAP];
    __shared__ int s_R;
    int tid = threadIdx.x;

    g_hist[tid] = 0u; g_hist[tid + 256] = 0u;    // reset for next replay
    if (tid == 0) g_cnt = 0u;

    if (tid < 64) {
        uint32_t fw = fglob[tid];
        f_s[tid] = fw;
        int cnt1 = __popc(fw);
        int pre = cnt1;
        for (int o = 1; o < 64; o <<= 1) {
            int v = __shfl_up(pre, o, 64);
            if (tid >= o) pre += v;
        }
        int r = pre - cnt1;                     // exclusive prefix
        while (fw) {
            int b = __ffs(fw) - 1; fw &= fw - 1;
            if (r < SUPCAP) rowlist[r] = tid * 32 + b;
            ++r;
        }
        if (tid == 63) s_R = pre;
    }
    __syncthreads();
    int R = s_R;
    bool sparse = (R <= SUPCAP);
    if (sparse) {                               // coalesced gathers, 16 in flight
        int s = tid >> 6, ln = tid & 63;
        while (s + 12 < R) {
            uint32_t a0 = MTT[(size_t)rowlist[s]      * 64 + ln];
            uint32_t a1 = MTT[(size_t)rowlist[s + 4]  * 64 + ln];
            uint32_t a2 = MTT[(size_t)rowlist[s + 8]  * 64 + ln];
            uint32_t a3 = MTT[(size_t)rowlist[s + 12] * 64 + ln];
            sup[s * 64 + ln] = a0;        sup[(s + 4) * 64 + ln] = a1;
            sup[(s + 8) * 64 + ln] = a2;  sup[(s + 12) * 64 + ln] = a3;
            s += 16;
        }
        for (; s < R; s += 4)
            sup[s * 64 + ln] = MTT[(size_t)rowlist[s] * 64 + ln];
    }
    __syncthreads();
    if (tid >= 64) return;

    int lane = tid;
    uint32_t removed = 0;
    #pragma unroll
    for (int b = 0; b < 32; ++b)
        if (!(sel_score[lane * 32 + b] > CONF_T)) removed |= (1u << b);

    if (sparse) {
        int slot = 0;
        for (int w = 0; w < 64; ++w) {
            uint32_t fb = f_s[w];               // wave-uniform
            while (fb) {
                int b = __ffs(fb) - 1; fb &= fb - 1;
                uint32_t rv = __shfl((int)removed, w, 64);
                if (!((rv >> b) & 1u))          // row kept -> apply suppression
                    removed |= sup[slot * 64 + lane];
                ++slot;
            }
        }
    } else {
        for (int c = 0; c < 64; ++c) {          // dense fallback (correctness net)
            uint32_t rw[32];
            #pragma unroll 8
            for (int b = 0; b < 32; ++b)
                rw[b] = MT[(size_t)lane * 2048 + c * 32 + b];
            uint32_t keptmask = 0;
            if (lane == c) {
                uint32_t myrem = removed;
                #pragma unroll
                for (int b = 0; b < 32; ++b)
                    if (!((myrem >> b) & 1u)) { keptmask |= (1u << b); myrem |= rw[b]; }
            }
            keptmask = __shfl(keptmask, c, 64);
            #pragma unroll
            for (int b = 0; b < 32; ++b)
                if ((keptmask >> b) & 1u) removed |= rw[b];
        }
    }

    uint32_t kw = ~removed;
    int cnt2 = __popc(kw);
    int pre = cnt2;
    for (int o = 1; o < 64; o <<= 1) {
        int v = __shfl_up(pre, o, 64);
        if (lane >= o) pre += v;
    }
    int excl = pre - cnt2;
    int total = __shfl(pre, 63, 64);

    int r = excl;
    for (int b = 0; b < 32; ++b) {
        if ((kw >> b) & 1u) {
            if (r < MAXDET) {
                const float* src = det_cand + (size_t)(lane * 32 + b) * 6;
                float* dst = det + (size_t)r * 6;
                for (int j = 0; j < 6; ++j) dst[j] = src[j];
            }
            ++r;
        }
    }
    int start = total < MAXDET ? total : MAXDET;
    for (int z = start + lane; z < MAXDET; z += 64) {
        float* dst = det + (size_t)z * 6;
        for (int j = 0; j < 6; ++j) dst[j] = 0.0f;
    }
}

// ------------------------------------------------------------------ launcher
extern "C" void kernel_launch(void* const* d_in, const int* in_sizes, int n_in,
                              void* d_out, int out_size, void* d_ws, size_t ws_size,
                              hipStream_t stream) {
    const int*   img  = (const int*)d_in[0];
    const float* pred = (const float*)d_in[1];   // (8,25200,85); only batch 0 used
    float* out = (float*)d_out;                  // det[1000*6] then x[1228800]
    char* ws = (char*)d_ws;

    float*    sel_score = (float*)(ws + WS_SELSCORE);
    float4*   selbox    = (float4*)(ws + WS_SELBOX);
    float*    det_cand  = (float*)(ws + WS_DETCAND);
    unsigned long long* rough = (unsigned long long*)(ws + WS_ROUGH);
    uint32_t* MT        = (uint32_t*)(ws + WS_MASK);
    uint32_t* MTT       = (uint32_t*)(ws + WS_MTT);
    uint32_t* fglob     = (uint32_t*)(ws + WS_F);
    float* xout = out + MAXDET * 6;

    prep_img_kernel<<<NSB + NIB, 256, 0, stream>>>(pred, img, xout, rough, fglob);
    rank_kernel<<<RKB, 256, 0, stream>>>(rough, pred, sel_score, selbox, det_cand);
    mask_kernel<<<512, 256, 0, stream>>>(selbox, MT, MTT, fglob);
    nms_kernel<<<1, 256, 0, stream>>>(MT, MTT, fglob, sel_score, det_cand, out);
}

// Round 8
// 134.395 us; speedup vs baseline: 1.2004x; 1.2004x over previous
//
#include <hip/hip_runtime.h>
#include <stdint.h>

#define N_ANCH 25200
#define NCLS   80
#define KSEL   2048
#define MAXDET 1000
#define CONF_T 0.4f
#define IOU_T  0.45f
#define MAX_WH 7680.0f
#define HBINS  512
#define HBASE  0xBE00u
#define NCAND_MAX 4096
#define NSB    788                  // prep blocks (32 anchors each)
#define NIB    400                  // img blocks (4 full px/thread)
#define SUPCAP 224                  // max flagged rows held in LDS
#define RKB    512                  // rank blocks (8 items each, 32 lanes/item)

// workspace layout (ws is ~267 MB per harness fill; we use < 1.5 MB)
#define WS_SELSCORE  0              // float  [2048]
#define WS_SELBOX    8192           // float4 [2048]
#define WS_DETCAND   40960          // float  [2048*6]   ends 90112
#define WS_CNT       92160          // uint32 [1]
#define WS_KEYS      92480          // uint32 [25200]    ends 193280
#define WS_CLS       193280         // int32  [25200]    ends 294080
#define WS_MASK      294912         // uint32 MT[64][2048]  ends 819200
#define WS_MTT       819200         // uint32 MTT[2048][64] ends 1343488
#define WS_F         1343488        // uint32 f[64] row-has-suppression bitmap
// cand[4096] u64 aliases the first 32 KB of MT: fully consumed by rank
// BEFORE mask overwrites MT (stream-ordered dispatches).
#define WS_CAND      294912

// ---------------------------------------------------------------- prep kernel
// score only: 8 lanes/anchor, strided class loads, shuffle argmax (exact
// product compare, first-occurrence ties), key write. Block 0 zeroes
// cnt/fglob (consumed 1 and 3 dispatches later; boundaries flush).
__global__ void __launch_bounds__(256)
prep_kernel(const float* __restrict__ pred0, uint32_t* __restrict__ keys,
            int* __restrict__ cls, uint32_t* __restrict__ cnt,
            uint32_t* __restrict__ fglob) {
    int tid = threadIdx.x;
    if (blockIdx.x == 0) {
        if (tid < 64) fglob[tid] = 0u;
        if (tid == 64) *cnt = 0u;
    }
    int lane = tid & 63, wave = tid >> 6;
    int g = lane >> 3, l = lane & 7;
    int a = blockIdx.x * 32 + wave * 8 + g;
    if (a >= N_ANCH) return;
    const float* p = pred0 + (size_t)a * 85;
    float obj = p[4];
    float v = -1e30f; int ci = 0;
    #pragma unroll
    for (int k = 0; k < 10; ++k) {
        int c = l + 8 * k;                 // classes 0..79 exactly
        float x = p[5 + c] * obj;          // exact product compare (matches ref)
        if (x > v) { v = x; ci = c; }      // increasing c: > = first occurrence
    }
    #pragma unroll
    for (int m = 1; m < 8; m <<= 1) {
        float ov = __shfl_xor(v, m, 64);
        int   oc = __shfl_xor(ci, m, 64);
        if (ov > v || (ov == v && oc < ci)) { v = ov; ci = oc; }
    }
    if (l == 0) {
        float score = (v > CONF_T) ? v : -1.0f;
        uint32_t bits = __float_as_uint(score);
        uint32_t key = (bits & 0x80000000u) ? ~bits : (bits | 0x80000000u);
        keys[a] = key; cls[a] = ci;
    }
}

// ------------------------------------------------------------- compact kernel
// blocks [0,25): LDS 512-bin hist from ALL keys (L2-hot) -> suffix scan ->
//   lim (r10 lesson: ~15K anchors exceed CONF_T, hist lim is ESSENTIAL);
//   per-thread match count; wave shuffle-scan; ONE atomicAdd/block; scatter.
// blocks [25,25+NIB): img transform rides along. 4 full px/thread
//   (3x int4 = 12 ints), one coalesced float4 per channel plane.
__global__ void __launch_bounds__(256)
compact_kernel(const uint32_t* __restrict__ keys, uint32_t* __restrict__ cnt,
               unsigned long long* __restrict__ cand,
               const int* __restrict__ img, float* __restrict__ xout) {
    __shared__ uint32_t h[HBINS];
    __shared__ uint32_t s_lim;
    __shared__ int wtot[4];
    __shared__ int s_base;
    int tid = threadIdx.x;

    if (blockIdx.x >= 25) {                    // ---- img role
        int i = (blockIdx.x - 25) * 256 + tid; // < 102400 exactly (NIB*256)
        const int4* im4 = (const int4*)(img + (size_t)i * 12);  // 48B-aligned
        int4 va = im4[0], vb4 = im4[1], vc = im4[2];
        int p0 = i * 4;
        // ints: [0]p0r [1]p0g [2]p0b [3]p1r [4]p1g [5]p1b ... [11]p3b
        float4 o0 = make_float4((float)va.z / 255.0f, (float)vb4.y / 255.0f,
                                (float)vc.x / 255.0f, (float)vc.w / 255.0f);
        float4 o1 = make_float4((float)va.y / 255.0f, (float)vb4.x / 255.0f,
                                (float)vb4.w / 255.0f, (float)vc.z / 255.0f);
        float4 o2 = make_float4((float)va.x / 255.0f, (float)va.w / 255.0f,
                                (float)vb4.z / 255.0f, (float)vc.y / 255.0f);
        *(float4*)(xout + p0)          = o0;   // plane 0 = img ch 2 (b)
        *(float4*)(xout + 409600 + p0) = o1;   // plane 1 = img ch 1 (g)
        *(float4*)(xout + 819200 + p0) = o2;   // plane 2 = img ch 0 (r)
        return;
    }

    // ---- compact role
    int lane = tid & 63, wv = tid >> 6;
    for (int b = tid; b < HBINS; b += 256) h[b] = 0u;
    if (tid == 0) s_lim = (HBASE << 16);
    __syncthreads();
    for (int i = tid; i < N_ANCH / 4; i += 256) {
        uint4 kk = ((const uint4*)keys)[i];
        if (kk.x >= (HBASE << 16)) atomicAdd(&h[(kk.x >> 16) - HBASE], 1u);
        if (kk.y >= (HBASE << 16)) atomicAdd(&h[(kk.y >> 16) - HBASE], 1u);
        if (kk.z >= (HBASE << 16)) atomicAdd(&h[(kk.z >> 16) - HBASE], 1u);
        if (kk.w >= (HBASE << 16)) atomicAdd(&h[(kk.w >> 16) - HBASE], 1u);
    }
    __syncthreads();
    for (int off = 1; off < HBINS; off <<= 1) {   // suffix scan
        uint32_t a0 = h[tid] + ((tid + off < HBINS) ? h[tid + off] : 0u);
        uint32_t a1 = h[tid + 256] + ((tid + 256 + off < HBINS) ? h[tid + 256 + off] : 0u);
        __syncthreads();
        h[tid] = a0; h[tid + 256] = a1;
        __syncthreads();
    }
    for (int b = tid; b < HBINS; b += 256) {
        uint32_t sb  = h[b];
        uint32_t sb1 = (b < HBINS - 1) ? h[b + 1] : 0u;
        if (sb >= KSEL && sb1 < KSEL) s_lim = (uint32_t)(HBASE + b) << 16;
    }
    __syncthreads();
    uint32_t lim = s_lim;

    int i = blockIdx.x * 256 + tid;            // uint4 index (6300 total)
    bool valid = (i < N_ANCH / 4);
    uint32_t ks[4] = {0, 0, 0, 0};
    int cm = 0;
    if (valid) {
        uint4 kk = ((const uint4*)keys)[i];
        ks[0] = kk.x; ks[1] = kk.y; ks[2] = kk.z; ks[3] = kk.w;
        #pragma unroll
        for (int j = 0; j < 4; ++j) cm += (ks[j] >= lim) ? 1 : 0;
    }
    int pre = cm;                               // wave inclusive scan
    #pragma unroll
    for (int o = 1; o < 64; o <<= 1) {
        int v = __shfl_up(pre, o, 64);
        if (lane >= o) pre += v;
    }
    if (lane == 63) wtot[wv] = pre;
    __syncthreads();
    if (tid == 0) {
        int t = 0;
        #pragma unroll
        for (int w = 0; w < 4; ++w) { int x = wtot[w]; wtot[w] = t; t += x; }
        s_base = (t > 0) ? (int)atomicAdd(cnt, (uint32_t)t) : 0;
    }
    __syncthreads();
    int pos = s_base + wtot[wv] + (pre - cm);   // exclusive global position
    if (valid) {
        #pragma unroll
        for (int j = 0; j < 4; ++j) {
            if (ks[j] >= lim) {
                if (pos < NCAND_MAX)
                    cand[pos] = ((unsigned long long)ks[j] << 32)
                              | (uint32_t)(~(uint32_t)(i * 4 + j));
                ++pos;
            }
        }
    }
}

// ---------------------------------------------------------------- rank kernel
// Latency-restructured (R5 lesson: rank is latency-bound, not work-bound):
// 512 blocks x 8 items, 32 lanes/item -> inner loop 64 iters (was 2x128),
// #pragma unroll 8 keeps 8 independent ds_read_b64 in flight (~120cyc LDS
// latency / 8). Blocks past ceil(n/8) exit before the LDS fill.
// rank = #{pack > mine}; emit at slot = rank (total order: idx breaks ties
// -> slots 0..2047 each written exactly once grid-wide).
__global__ void __launch_bounds__(256)
rank_kernel(const uint32_t* __restrict__ cnt, const unsigned long long* __restrict__ cand,
            const float* __restrict__ pred0, const int* __restrict__ cls,
            float* __restrict__ sel_score, float4* __restrict__ selbox,
            float* __restrict__ det_cand) {
    __shared__ unsigned long long s_it[NCAND_MAX];
    __shared__ int s_n;
    int tid = threadIdx.x;
    if (tid == 0) s_n = (int)min(*cnt, (uint32_t)NCAND_MAX);
    __syncthreads();
    int n = s_n;
    int base = blockIdx.x * 8;
    if (base >= n) return;
    #pragma unroll 4
    for (int i = tid; i < n; i += 256) s_it[i] = cand[i];
    __syncthreads();
    int grp = tid >> 5, s32 = tid & 31;
    int it = base + grp;
    if (it < n) {                               // uniform within 32-lane group
        unsigned long long mine = s_it[it];
        int c = 0;
        #pragma unroll 8
        for (int t = s32; t < n; t += 32)       // independent LDS reads
            c += (s_it[t] > mine) ? 1 : 0;
        #pragma unroll
        for (int m = 1; m < 32; m <<= 1) c += __shfl_xor(c, m, 64);  // within 32-half
        if (s32 == 0 && c < KSEL) {
            uint32_t key = (uint32_t)(mine >> 32);
            int ai = (int)(~(uint32_t)mine);
            uint32_t fb = (key & 0x80000000u) ? (key & 0x7FFFFFFFu) : ~key;
            float score = __uint_as_float(fb);
            const float* p = pred0 + (size_t)ai * 85;
            float x = p[0], y = p[1], w = p[2], hh = p[3];
            float x1 = x - w * 0.5f, y1 = y - hh * 0.5f;
            float x2 = x + w * 0.5f, y2 = y + hh * 0.5f;
            float cf = (float)cls[ai];
            float off = cf * MAX_WH;
            selbox[c] = make_float4(x1 + off, y1 + off, x2 + off, y2 + off);
            float* dc = det_cand + (size_t)c * 6;
            dc[0] = x1; dc[1] = y1; dc[2] = x2; dc[3] = y2; dc[4] = score; dc[5] = cf;
            sel_score[c] = score;
        }
    }
}

// ----------------------------------------------------------------- mask kernel
// 512 blocks: block (wi = blk>>3, rg = blk&7) computes MT[wi][rg*256+tid]
// (coalesced) + transposed MTT[row][wi] (makes nms gather coalesced) + f
// bitmap via one ballot per wave -> atomicOr. Plain stores: the dispatch
// boundary to nms provides cross-XCD coherence (R4 lesson: sc1 costs more).
__global__ void __launch_bounds__(256)
mask_kernel(const float4* __restrict__ selbox, uint32_t* __restrict__ MT,
            uint32_t* __restrict__ MTT, uint32_t* __restrict__ fglob) {
    __shared__ float4 jb[32];
    int tid = threadIdx.x;
    int lane = tid & 63, wv = tid >> 6;
    int wi = blockIdx.x >> 3, rg = blockIdx.x & 7;

    if (tid < 32) jb[tid] = selbox[wi * 32 + tid];
    __syncthreads();
    int row = rg * 256 + tid;
    float4 a = selbox[row];
    float areaA = (a.z - a.x) * (a.w - a.y);
    uint32_t bits = 0;
    #pragma unroll 4
    for (int b = 0; b < 32; ++b) {
        int j = wi * 32 + b;
        if (j > row) {
            float4 q = jb[b];
            float lx = fmaxf(a.x, q.x), ly = fmaxf(a.y, q.y);
            float rx = fminf(a.z, q.z), ry = fminf(a.w, q.w);
            float ww = fmaxf(rx - lx, 0.0f), hh = fmaxf(ry - ly, 0.0f);
            float inter = ww * hh;
            float areaB = (q.z - q.x) * (q.w - q.y);
            float iou = inter / (areaA + areaB - inter + 1e-7f);
            if (iou > IOU_T) bits |= (1u << b);
        }
    }
    MT[(size_t)wi * 2048 + row] = bits;
    MTT[(size_t)row * 64 + wi] = bits;
    unsigned long long bm = __ballot(bits != 0u);   // wave = 64 rows = 2 words
    if (lane == 0) {
        int wbase = rg * 8 + wv * 2;
        uint32_t lo = (uint32_t)bm, hi = (uint32_t)(bm >> 32);
        if (lo) atomicOr(&fglob[wbase], lo);
        if (hi) atomicOr(&fglob[wbase + 1], hi);
    }
}

// ------------------------------------------------------------------ nms kernel
// One block. Read f[64]; parallel rowlist build; gather flagged rows from MTT
// (coalesced 256B per row, 16 rows in flight); one-wave sparse walk; emit +
// zero-fill.
__global__ void __launch_bounds__(256)
nms_kernel(const uint32_t* __restrict__ MT, const uint32_t* __restrict__ MTT,
           const uint32_t* __restrict__ fglob, const float* __restrict__ sel_score,
           const float* __restrict__ det_cand, float* __restrict__ det) {
    __shared__ __align__(16) uint32_t sup[SUPCAP * 64];  // 56 KB
    __shared__ uint32_t f_s[64];
    __shared__ int rowlist[SUPCAP];
    __shared__ int s_R;
    int tid = threadIdx.x;

    if (tid < 64) {
        uint32_t fw = fglob[tid];
        f_s[tid] = fw;
        int cnt1 = __popc(fw);
        int pre = cnt1;
        for (int o = 1; o < 64; o <<= 1) {
            int v = __shfl_up(pre, o, 64);
            if (tid >= o) pre += v;
        }
        int r = pre - cnt1;                     // exclusive prefix
        while (fw) {
            int b = __ffs(fw) - 1; fw &= fw - 1;
            if (r < SUPCAP) rowlist[r] = tid * 32 + b;
            ++r;
        }
        if (tid == 63) s_R = pre;
    }
    __syncthreads();
    int R = s_R;
    bool sparse = (R <= SUPCAP);
    if (sparse) {                               // coalesced gathers, 16 in flight
        int s = tid >> 6, ln = tid & 63;
        while (s + 12 < R) {
            uint32_t a0 = MTT[(size_t)rowlist[s]      * 64 + ln];
            uint32_t a1 = MTT[(size_t)rowlist[s + 4]  * 64 + ln];
            uint32_t a2 = MTT[(size_t)rowlist[s + 8]  * 64 + ln];
            uint32_t a3 = MTT[(size_t)rowlist[s + 12] * 64 + ln];
            sup[s * 64 + ln] = a0;        sup[(s + 4) * 64 + ln] = a1;
            sup[(s + 8) * 64 + ln] = a2;  sup[(s + 12) * 64 + ln] = a3;
            s += 16;
        }
        for (; s < R; s += 4)
            sup[s * 64 + ln] = MTT[(size_t)rowlist[s] * 64 + ln];
    }
    __syncthreads();
    if (tid >= 64) return;

    int lane = tid;
    uint32_t removed = 0;
    #pragma unroll
    for (int b = 0; b < 32; ++b)
        if (!(sel_score[lane * 32 + b] > CONF_T)) removed |= (1u << b);

    if (sparse) {
        int slot = 0;
        for (int w = 0; w < 64; ++w) {
            uint32_t fb = f_s[w];               // wave-uniform
            while (fb) {
                int b = __ffs(fb) - 1; fb &= fb - 1;
                uint32_t rv = __shfl((int)removed, w, 64);
                if (!((rv >> b) & 1u))          // row kept -> apply suppression
                    removed |= sup[slot * 64 + lane];
                ++slot;
            }
        }
    } else {
        for (int c = 0; c < 64; ++c) {          // dense fallback (correctness net)
            uint32_t rw[32];
            #pragma unroll 8
            for (int b = 0; b < 32; ++b)
                rw[b] = MT[(size_t)lane * 2048 + c * 32 + b];
            uint32_t keptmask = 0;
            if (lane == c) {
                uint32_t myrem = removed;
                #pragma unroll
                for (int b = 0; b < 32; ++b)
                    if (!((myrem >> b) & 1u)) { keptmask |= (1u << b); myrem |= rw[b]; }
            }
            keptmask = __shfl(keptmask, c, 64);
            #pragma unroll
            for (int b = 0; b < 32; ++b)
                if ((keptmask >> b) & 1u) removed |= rw[b];
        }
    }

    uint32_t kw = ~removed;
    int cnt2 = __popc(kw);
    int pre = cnt2;
    for (int o = 1; o < 64; o <<= 1) {
        int v = __shfl_up(pre, o, 64);
        if (lane >= o) pre += v;
    }
    int excl = pre - cnt2;
    int total = __shfl(pre, 63, 64);

    int r = excl;
    for (int b = 0; b < 32; ++b) {
        if ((kw >> b) & 1u) {
            if (r < MAXDET) {
                const float* src = det_cand + (size_t)(lane * 32 + b) * 6;
                float* dst = det + (size_t)r * 6;
                for (int j = 0; j < 6; ++j) dst[j] = src[j];
            }
            ++r;
        }
    }
    int start = total < MAXDET ? total : MAXDET;
    for (int z = start + lane; z < MAXDET; z += 64) {
        float* dst = det + (size_t)z * 6;
        for (int j = 0; j < 6; ++j) dst[j] = 0.0f;
    }
}

// ------------------------------------------------------------------ launcher
extern "C" void kernel_launch(void* const* d_in, const int* in_sizes, int n_in,
                              void* d_out, int out_size, void* d_ws, size_t ws_size,
                              hipStream_t stream) {
    const int*   img  = (const int*)d_in[0];
    const float* pred = (const float*)d_in[1];   // (8,25200,85); only batch 0 used
    float* out = (float*)d_out;                  // det[1000*6] then x[1228800]
    char* ws = (char*)d_ws;

    float*    sel_score = (float*)(ws + WS_SELSCORE);
    float4*   selbox    = (float4*)(ws + WS_SELBOX);
    float*    det_cand  = (float*)(ws + WS_DETCAND);
    uint32_t* cnt       = (uint32_t*)(ws + WS_CNT);
    uint32_t* keys      = (uint32_t*)(ws + WS_KEYS);
    int*      cls       = (int*)(ws + WS_CLS);
    uint32_t* MT        = (uint32_t*)(ws + WS_MASK);
    uint32_t* MTT       = (uint32_t*)(ws + WS_MTT);
    uint32_t* fglob     = (uint32_t*)(ws + WS_F);
    unsigned long long* cand = (unsigned long long*)(ws + WS_CAND);  // aliases MT head
    float* xout = out + MAXDET * 6;

    prep_kernel<<<NSB, 256, 0, stream>>>(pred, keys, cls, cnt, fglob);
    compact_kernel<<<25 + NIB, 256, 0, stream>>>(keys, cnt, cand, img, xout);
    rank_kernel<<<RKB, 256, 0, stream>>>(cnt, cand, pred, cls,
                                         sel_score, selbox, det_cand);
    mask_kernel<<<512, 256, 0, stream>>>(selbox, MT, MTT, fglob);
    nms_kernel<<<1, 256, 0, stream>>>(MT, MTT, fglob, sel_score, det_cand, out);
}